// Round 4
// baseline (560.137 us; speedup 1.0000x reference)
//
#include <hip/hip_runtime.h>
#include <stdint.h>

typedef unsigned short u16;
typedef __bf16 bf16x8 __attribute__((ext_vector_type(8)));
typedef float f32x4 __attribute__((ext_vector_type(4)));

#define NROWS 8192
#define DDIM 512

// async global->LDS, 16B per lane. Dest must be wave-uniform base + lane*16
// (our staging layout satisfies this: thread t owns LDS bytes [t*16, t*16+16)).
#define GLOAD_LDS16(g, l)                                            \
  __builtin_amdgcn_global_load_lds(                                  \
      (const __attribute__((address_space(1))) void*)(g),            \
      (__attribute__((address_space(3))) void*)(l), 16, 0, 0)

__device__ __forceinline__ u16 f32_to_bf16(float f) {
  union { float f; unsigned u; } v; v.f = f;
  unsigned r = v.u + 0x7fffu + ((v.u >> 16) & 1u);
  return (u16)(r >> 16);
}

// ---------------- cast f32 -> bf16 (vectorized x4) ----------------
__global__ void cast_f32_bf16(const float* __restrict__ in, u16* __restrict__ out, int n4) {
  int i = blockIdx.x * blockDim.x + threadIdx.x;
  if (i < n4) {
    float4 v = reinterpret_cast<const float4*>(in)[i];
    ushort4 o;
    o.x = f32_to_bf16(v.x); o.y = f32_to_bf16(v.y);
    o.z = f32_to_bf16(v.z); o.w = f32_to_bf16(v.w);
    reinterpret_cast<ushort4*>(out)[i] = o;
  }
}

// ---------------- gemm_bt: C[i,j] = sum_k A[i,k]*B[j,k], K=512 ----------------
// EPI 0: outB[i,j] = bf16(elu(C + bias[j]))        (N stride 512)
// EPI 1: outF[i,j] = C + bias[j]                    (N stride 512)
// EPI 2: rowsum[i] += sum_j exp(2*C[i,j]); if COLSUM: colsum[j] += sum_i exp(2*C[i,j])
template <int EPI, bool COLSUM>
__global__ void __launch_bounds__(256)
gemm_bt(const u16* __restrict__ A, const u16* __restrict__ B,
        const float* __restrict__ bias,
        u16* __restrict__ outB, float* __restrict__ outF,
        float* __restrict__ rowsum, float* __restrict__ colsum)
{
  constexpr int K = 512;
  __shared__ __align__(16) u16 As[128 * 32];
  __shared__ __align__(16) u16 Bs[128 * 32];

  const int t = threadIdx.x;
  const int lane = t & 63;
  const int w = t >> 6;          // wave 0..3
  const int wr = w >> 1, wc = w & 1;
  const int tileM = blockIdx.y * 128;
  const int tileN = blockIdx.x * 128;

  // staging: 512 chunks of 16B per tile (A and B each); thread handles chunks t, t+256
  const int q0 = t, q1 = t + 256;
  const int r0 = q0 >> 2, c0 = (q0 & 3) * 8;
  const int r1 = q1 >> 2, c1 = (q1 & 3) * 8;
  const u16* Ap0 = A + (size_t)(tileM + r0) * K + c0;
  const u16* Ap1 = A + (size_t)(tileM + r1) * K + c1;
  const u16* Bp0 = B + (size_t)(tileN + r0) * K + c0;
  const u16* Bp1 = B + (size_t)(tileN + r1) * K + c1;

  f32x4 acc[4][4] = {};

  const int lrow = lane & 15;          // row within 16x16 fragment (A/B operand)
  const int kb = (lane >> 4) * 8;      // k-slice base

  for (int k0 = 0; k0 < K; k0 += 32) {
    __syncthreads();                    // protect LDS reads of previous iter
    GLOAD_LDS16(Ap0 + k0, &As[q0 * 8]);
    GLOAD_LDS16(Ap1 + k0, &As[q1 * 8]);
    GLOAD_LDS16(Bp0 + k0, &Bs[q0 * 8]);
    GLOAD_LDS16(Bp1 + k0, &Bs[q1 * 8]);
    __syncthreads();                    // drains vmcnt -> staged data visible

    bf16x8 af[4], bfr[4];
#pragma unroll
    for (int m = 0; m < 4; m++)
      af[m] = *(const bf16x8*)&As[(wr * 64 + m * 16 + lrow) * 32 + kb];
#pragma unroll
    for (int n = 0; n < 4; n++)
      bfr[n] = *(const bf16x8*)&Bs[(wc * 64 + n * 16 + lrow) * 32 + kb];
#pragma unroll
    for (int m = 0; m < 4; m++)
#pragma unroll
      for (int n = 0; n < 4; n++)
        acc[m][n] = __builtin_amdgcn_mfma_f32_16x16x32_bf16(af[m], bfr[n], acc[m][n], 0, 0, 0);
  }

  // epilogue: C/D layout col = lane&15, row = (lane>>4)*4 + reg  [m89/m91 verified]
  const int rowg = (lane >> 4) * 4;
  const int col = lane & 15;

  if (EPI == 0 || EPI == 1) {
#pragma unroll
    for (int m = 0; m < 4; m++) {
      int grow = tileM + wr * 64 + m * 16 + rowg;
#pragma unroll
      for (int n = 0; n < 4; n++) {
        int gcol = tileN + wc * 64 + n * 16 + col;
        float bv = bias[gcol];
#pragma unroll
        for (int r = 0; r < 4; r++) {
          float v = acc[m][n][r] + bv;
          if (EPI == 0) {
            v = v > 0.0f ? v : (__expf(v) - 1.0f);
            outB[(size_t)(grow + r) * 512 + gcol] = f32_to_bf16(v);
          } else {
            outF[(size_t)(grow + r) * 512 + gcol] = v;
          }
        }
      }
    }
  } else {
    // exp + row reduction
#pragma unroll
    for (int m = 0; m < 4; m++) {
#pragma unroll
      for (int r = 0; r < 4; r++) {
        float s = 0.0f;
#pragma unroll
        for (int n = 0; n < 4; n++) {
          float e = __expf(acc[m][n][r] * 2.0f);
          acc[m][n][r] = e;
          s += e;
        }
        s += __shfl_xor(s, 1);
        s += __shfl_xor(s, 2);
        s += __shfl_xor(s, 4);
        s += __shfl_xor(s, 8);
        if (col == 0)
          atomicAdd(&rowsum[tileM + wr * 64 + m * 16 + rowg + r], s);
      }
    }
    if (COLSUM) {
#pragma unroll
      for (int n = 0; n < 4; n++) {
        float s = 0.0f;
#pragma unroll
        for (int m = 0; m < 4; m++)
#pragma unroll
          for (int r = 0; r < 4; r++) s += acc[m][n][r];
        s += __shfl_xor(s, 16);
        s += __shfl_xor(s, 32);
        if ((lane >> 4) == 0)
          atomicAdd(&colsum[tileN + wc * 64 + n * 16 + col], s);
      }
    }
  }
}

// ---------------- row-normalize p1,p2 -> bf16; d12[i] = cos(p1_i, p2_i) ----------------
__global__ void __launch_bounds__(256)
normalize_rows(const float* __restrict__ p1, const float* __restrict__ p2,
               u16* __restrict__ n1, u16* __restrict__ n2, float* __restrict__ d12)
{
  int row = blockIdx.x;
  int t = threadIdx.x;
  const float* r1 = p1 + (size_t)row * 512;
  const float* r2 = p2 + (size_t)row * 512;
  float a0 = r1[t], a1 = r1[t + 256];
  float b0 = r2[t], b1 = r2[t + 256];
  float ss1 = a0 * a0 + a1 * a1;
  float ss2 = b0 * b0 + b1 * b1;
  float dt  = a0 * b0 + a1 * b1;
#pragma unroll
  for (int m = 1; m < 64; m <<= 1) {
    ss1 += __shfl_xor(ss1, m);
    ss2 += __shfl_xor(ss2, m);
    dt  += __shfl_xor(dt, m);
  }
  __shared__ float sh[3][4];
  int w = t >> 6;
  if ((t & 63) == 0) { sh[0][w] = ss1; sh[1][w] = ss2; sh[2][w] = dt; }
  __syncthreads();
  ss1 = sh[0][0] + sh[0][1] + sh[0][2] + sh[0][3];
  ss2 = sh[1][0] + sh[1][1] + sh[1][2] + sh[1][3];
  dt  = sh[2][0] + sh[2][1] + sh[2][2] + sh[2][3];
  float i1 = 1.0f / fmaxf(sqrtf(ss1), 1e-12f);
  float i2 = 1.0f / fmaxf(sqrtf(ss2), 1e-12f);
  n1[(size_t)row * 512 + t]       = f32_to_bf16(a0 * i1);
  n1[(size_t)row * 512 + t + 256] = f32_to_bf16(a1 * i1);
  n2[(size_t)row * 512 + t]       = f32_to_bf16(b0 * i2);
  n2[(size_t)row * 512 + t + 256] = f32_to_bf16(b1 * i2);
  if (t == 0) d12[row] = dt * i1 * i2;
}

// ---------------- final loss ----------------
__global__ void __launch_bounds__(256)
loss_reduce(const float* __restrict__ rs11, const float* __restrict__ rs12,
            const float* __restrict__ cs12, const float* __restrict__ rs22,
            const float* __restrict__ d12, float* __restrict__ out)
{
  int t = threadIdx.x;
  const float e2 = __expf(2.0f);
  float s = 0.0f;
  for (int i = t; i < NROWS; i += 256) {
    float den1 = rs11[i] + rs12[i] - e2;
    float den2 = rs22[i] + cs12[i] - e2;
    s += 0.5f * (logf(den1) + logf(den2)) - 2.0f * d12[i];
  }
#pragma unroll
  for (int m = 1; m < 64; m <<= 1) s += __shfl_xor(s, m);
  __shared__ float sh[4];
  if ((t & 63) == 0) sh[t >> 6] = s;
  __syncthreads();
  if (t == 0) out[0] = (sh[0] + sh[1] + sh[2] + sh[3]) * (1.0f / (float)NROWS);
}

extern "C" void kernel_launch(void* const* d_in, const int* in_sizes, int n_in,
                              void* d_out, int out_size, void* d_ws, size_t ws_size,
                              hipStream_t stream) {
  (void)in_sizes; (void)n_in; (void)out_size; (void)ws_size;
  const float* pri = (const float*)d_in[0];
  const float* aux = (const float*)d_in[1];
  const float* W1  = (const float*)d_in[2];
  const float* b1  = (const float*)d_in[3];
  const float* W2  = (const float*)d_in[4];
  const float* b2  = (const float*)d_in[5];
  float* out = (float*)d_out;

  const int N = NROWS, D = DDIM;
  char* ws = (char*)d_ws;
  size_t off = 0;
  auto alloc = [&](size_t bytes) -> void* {
    void* p = ws + off;
    off += (bytes + 255) & ~(size_t)255;
    return p;
  };
  u16* prib = (u16*)alloc((size_t)N * D * 2);
  u16* auxb = (u16*)alloc((size_t)N * D * 2);
  u16* W1b  = (u16*)alloc((size_t)D * D * 2);
  u16* W2b  = (u16*)alloc((size_t)D * D * 2);
  u16* h1b  = (u16*)alloc((size_t)N * D * 2);
  u16* h2b  = (u16*)alloc((size_t)N * D * 2);
  float* p1 = (float*)alloc((size_t)N * D * 4);
  float* p2 = (float*)alloc((size_t)N * D * 4);
  u16* n1b  = (u16*)alloc((size_t)N * D * 2);
  u16* n2b  = (u16*)alloc((size_t)N * D * 2);
  float* d12  = (float*)alloc((size_t)N * 4);
  float* rs11 = (float*)alloc((size_t)N * 4);
  float* rs12 = (float*)alloc((size_t)N * 4);
  float* cs12 = (float*)alloc((size_t)N * 4);
  float* rs22 = (float*)alloc((size_t)N * 4);

  // zero the 4 reduction arrays (contiguous, 32KB each)
  hipMemsetAsync(rs11, 0, (size_t)4 * N * 4, stream);

  // casts
  cast_f32_bf16<<<(N * D / 4 + 255) / 256, 256, 0, stream>>>(pri, prib, N * D / 4);
  cast_f32_bf16<<<(N * D / 4 + 255) / 256, 256, 0, stream>>>(aux, auxb, N * D / 4);
  cast_f32_bf16<<<(D * D / 4 + 255) / 256, 256, 0, stream>>>(W1, W1b, D * D / 4);
  cast_f32_bf16<<<(D * D / 4 + 255) / 256, 256, 0, stream>>>(W2, W2b, D * D / 4);

  // projections: h = elu(z @ W1^T + b1) ; p = h @ W2^T + b2
  dim3 gproj(D / 128, N / 128);
  gemm_bt<0, false><<<gproj, 256, 0, stream>>>(prib, W1b, b1, h1b, nullptr, nullptr, nullptr);
  gemm_bt<0, false><<<gproj, 256, 0, stream>>>(auxb, W1b, b1, h2b, nullptr, nullptr, nullptr);
  gemm_bt<1, false><<<gproj, 256, 0, stream>>>(h1b, W2b, b2, nullptr, p1, nullptr, nullptr);
  gemm_bt<1, false><<<gproj, 256, 0, stream>>>(h2b, W2b, b2, nullptr, p2, nullptr, nullptr);

  // normalize + diag(S12)
  normalize_rows<<<N, 256, 0, stream>>>(p1, p2, n1b, n2b, d12);

  // similarity exp-sums
  dim3 gsim(N / 128, N / 128);
  gemm_bt<2, false><<<gsim, 256, 0, stream>>>(n1b, n1b, nullptr, nullptr, nullptr, rs11, nullptr);
  gemm_bt<2, true ><<<gsim, 256, 0, stream>>>(n1b, n2b, nullptr, nullptr, nullptr, rs12, cs12);
  gemm_bt<2, false><<<gsim, 256, 0, stream>>>(n2b, n2b, nullptr, nullptr, nullptr, rs22, nullptr);

  // final scalar
  loss_reduce<<<1, 256, 0, stream>>>(rs11, rs12, cs12, rs22, d12, out);
}

// Round 5
// 443.031 us; speedup vs baseline: 1.2643x; 1.2643x over previous
//
#include <hip/hip_runtime.h>
#include <stdint.h>

typedef unsigned short u16;
typedef __bf16 bf16x8 __attribute__((ext_vector_type(8)));
typedef float f32x4 __attribute__((ext_vector_type(4)));

#define NROWS 8192
#define DDIM 512

// async global->LDS, 16B per lane. Dest must be wave-uniform base + lane*16
// (our staging layout satisfies this: thread t owns LDS bytes [t*16, t*16+16)).
#define GLOAD_LDS16(g, l)                                            \
  __builtin_amdgcn_global_load_lds(                                  \
      (const __attribute__((address_space(1))) void*)(g),            \
      (__attribute__((address_space(3))) void*)(l), 16, 0, 0)

__device__ __forceinline__ u16 f32_to_bf16(float f) {
  union { float f; unsigned u; } v; v.f = f;
  unsigned r = v.u + 0x7fffu + ((v.u >> 16) & 1u);
  return (u16)(r >> 16);
}

// ---------------- cast f32 -> bf16 (vectorized x4) ----------------
__global__ void cast_f32_bf16(const float* __restrict__ in, u16* __restrict__ out, int n4) {
  int i = blockIdx.x * blockDim.x + threadIdx.x;
  if (i < n4) {
    float4 v = reinterpret_cast<const float4*>(in)[i];
    ushort4 o;
    o.x = f32_to_bf16(v.x); o.y = f32_to_bf16(v.y);
    o.z = f32_to_bf16(v.z); o.w = f32_to_bf16(v.w);
    reinterpret_cast<ushort4*>(out)[i] = o;
  }
}

// ---------------- gemm_bt: C[i,j] = sum_k A[i,k]*B[j,k], K=512 ----------------
// EPI 0: outB[i,j] = bf16(elu(C + bias[j]))
// EPI 1: outF[i,j] = C + bias[j]
// EPI 2: rowsum[i] += sum_j exp(2C); colsum[j] += sum_i exp(2C)
// EPI 3: symmetric input (A==B): upper-triangle grid only (bx>=by);
//        rowsum[i] += sum_j exp(2C); off-diag blocks also mirror their
//        column sums into rowsum[tileN rows] (S[j,i] == S[i,j]).
template <int EPI>
__global__ void __launch_bounds__(256)
gemm_bt(const u16* __restrict__ A, const u16* __restrict__ B,
        const float* __restrict__ bias,
        u16* __restrict__ outB, float* __restrict__ outF,
        float* __restrict__ rowsum, float* __restrict__ colsum)
{
  if (EPI == 3 && blockIdx.x < blockIdx.y) return;  // uniform early-exit

  constexpr int K = 512;
  __shared__ __align__(16) u16 As[128 * 32];
  __shared__ __align__(16) u16 Bs[128 * 32];

  const int t = threadIdx.x;
  const int lane = t & 63;
  const int w = t >> 6;          // wave 0..3
  const int wr = w >> 1, wc = w & 1;
  const int tileM = blockIdx.y * 128;
  const int tileN = blockIdx.x * 128;

  // staging: 512 chunks of 16B per tile (A and B each); thread handles chunks t, t+256
  const int q0 = t, q1 = t + 256;
  const int r0 = q0 >> 2, c0 = (q0 & 3) * 8;
  const int r1 = q1 >> 2, c1 = (q1 & 3) * 8;
  const u16* Ap0 = A + (size_t)(tileM + r0) * K + c0;
  const u16* Ap1 = A + (size_t)(tileM + r1) * K + c1;
  const u16* Bp0 = B + (size_t)(tileN + r0) * K + c0;
  const u16* Bp1 = B + (size_t)(tileN + r1) * K + c1;

  f32x4 acc[4][4] = {};

  const int lrow = lane & 15;          // row within 16x16 fragment (A/B operand)
  const int kb = (lane >> 4) * 8;      // k-slice base

  for (int k0 = 0; k0 < K; k0 += 32) {
    __syncthreads();                    // protect LDS reads of previous iter
    GLOAD_LDS16(Ap0 + k0, &As[q0 * 8]);
    GLOAD_LDS16(Ap1 + k0, &As[q1 * 8]);
    GLOAD_LDS16(Bp0 + k0, &Bs[q0 * 8]);
    GLOAD_LDS16(Bp1 + k0, &Bs[q1 * 8]);
    __syncthreads();                    // drains vmcnt -> staged data visible

    bf16x8 af[4], bfr[4];
#pragma unroll
    for (int m = 0; m < 4; m++)
      af[m] = *(const bf16x8*)&As[(wr * 64 + m * 16 + lrow) * 32 + kb];
#pragma unroll
    for (int n = 0; n < 4; n++)
      bfr[n] = *(const bf16x8*)&Bs[(wc * 64 + n * 16 + lrow) * 32 + kb];
#pragma unroll
    for (int m = 0; m < 4; m++)
#pragma unroll
      for (int n = 0; n < 4; n++)
        acc[m][n] = __builtin_amdgcn_mfma_f32_16x16x32_bf16(af[m], bfr[n], acc[m][n], 0, 0, 0);
  }

  // epilogue: C/D layout col = lane&15, row = (lane>>4)*4 + reg  [m89/m91 verified]
  const int rowg = (lane >> 4) * 4;
  const int col = lane & 15;

  if (EPI == 0 || EPI == 1) {
#pragma unroll
    for (int m = 0; m < 4; m++) {
      int grow = tileM + wr * 64 + m * 16 + rowg;
#pragma unroll
      for (int n = 0; n < 4; n++) {
        int gcol = tileN + wc * 64 + n * 16 + col;
        float bv = bias[gcol];
#pragma unroll
        for (int r = 0; r < 4; r++) {
          float v = acc[m][n][r] + bv;
          if (EPI == 0) {
            v = v > 0.0f ? v : (__expf(v) - 1.0f);
            outB[(size_t)(grow + r) * 512 + gcol] = f32_to_bf16(v);
          } else {
            outF[(size_t)(grow + r) * 512 + gcol] = v;
          }
        }
      }
    }
  } else {
    // exp(2C) + row reduction (all EPI 2/3)
#pragma unroll
    for (int m = 0; m < 4; m++) {
#pragma unroll
      for (int r = 0; r < 4; r++) {
        float s = 0.0f;
#pragma unroll
        for (int n = 0; n < 4; n++) {
          float e = __expf(acc[m][n][r] * 2.0f);
          acc[m][n][r] = e;
          s += e;
        }
        s += __shfl_xor(s, 1);
        s += __shfl_xor(s, 2);
        s += __shfl_xor(s, 4);
        s += __shfl_xor(s, 8);
        if (col == 0)
          atomicAdd(&rowsum[tileM + wr * 64 + m * 16 + rowg + r], s);
      }
    }
    // column reduction: EPI 2 -> colsum array; EPI 3 off-diag -> mirrored rowsum
    if (EPI == 2 || (EPI == 3 && tileM != tileN)) {
      float* cdst = (EPI == 2) ? colsum : rowsum;
#pragma unroll
      for (int n = 0; n < 4; n++) {
        float s = 0.0f;
#pragma unroll
        for (int m = 0; m < 4; m++)
#pragma unroll
          for (int r = 0; r < 4; r++) s += acc[m][n][r];
        s += __shfl_xor(s, 16);
        s += __shfl_xor(s, 32);
        if ((lane >> 4) == 0)
          atomicAdd(&cdst[tileN + wc * 64 + n * 16 + col], s);
      }
    }
  }
}

// ---------------- row-normalize p1,p2 -> bf16; d12[i] = cos(p1_i, p2_i) ----------------
__global__ void __launch_bounds__(256)
normalize_rows(const float* __restrict__ p1, const float* __restrict__ p2,
               u16* __restrict__ n1, u16* __restrict__ n2, float* __restrict__ d12)
{
  int row = blockIdx.x;
  int t = threadIdx.x;
  const float* r1 = p1 + (size_t)row * 512;
  const float* r2 = p2 + (size_t)row * 512;
  float a0 = r1[t], a1 = r1[t + 256];
  float b0 = r2[t], b1 = r2[t + 256];
  float ss1 = a0 * a0 + a1 * a1;
  float ss2 = b0 * b0 + b1 * b1;
  float dt  = a0 * b0 + a1 * b1;
#pragma unroll
  for (int m = 1; m < 64; m <<= 1) {
    ss1 += __shfl_xor(ss1, m);
    ss2 += __shfl_xor(ss2, m);
    dt  += __shfl_xor(dt, m);
  }
  __shared__ float sh[3][4];
  int w = t >> 6;
  if ((t & 63) == 0) { sh[0][w] = ss1; sh[1][w] = ss2; sh[2][w] = dt; }
  __syncthreads();
  ss1 = sh[0][0] + sh[0][1] + sh[0][2] + sh[0][3];
  ss2 = sh[1][0] + sh[1][1] + sh[1][2] + sh[1][3];
  dt  = sh[2][0] + sh[2][1] + sh[2][2] + sh[2][3];
  float i1 = 1.0f / fmaxf(sqrtf(ss1), 1e-12f);
  float i2 = 1.0f / fmaxf(sqrtf(ss2), 1e-12f);
  n1[(size_t)row * 512 + t]       = f32_to_bf16(a0 * i1);
  n1[(size_t)row * 512 + t + 256] = f32_to_bf16(a1 * i1);
  n2[(size_t)row * 512 + t]       = f32_to_bf16(b0 * i2);
  n2[(size_t)row * 512 + t + 256] = f32_to_bf16(b1 * i2);
  if (t == 0) d12[row] = dt * i1 * i2;
}

// ---------------- final loss ----------------
__global__ void __launch_bounds__(256)
loss_reduce(const float* __restrict__ rs11, const float* __restrict__ rs12,
            const float* __restrict__ cs12, const float* __restrict__ rs22,
            const float* __restrict__ d12, float* __restrict__ out)
{
  int t = threadIdx.x;
  const float e2 = __expf(2.0f);
  float s = 0.0f;
  for (int i = t; i < NROWS; i += 256) {
    float den1 = rs11[i] + rs12[i] - e2;
    float den2 = rs22[i] + cs12[i] - e2;
    s += 0.5f * (logf(den1) + logf(den2)) - 2.0f * d12[i];
  }
#pragma unroll
  for (int m = 1; m < 64; m <<= 1) s += __shfl_xor(s, m);
  __shared__ float sh[4];
  if ((t & 63) == 0) sh[t >> 6] = s;
  __syncthreads();
  if (t == 0) out[0] = (sh[0] + sh[1] + sh[2] + sh[3]) * (1.0f / (float)NROWS);
}

extern "C" void kernel_launch(void* const* d_in, const int* in_sizes, int n_in,
                              void* d_out, int out_size, void* d_ws, size_t ws_size,
                              hipStream_t stream) {
  (void)in_sizes; (void)n_in; (void)out_size; (void)ws_size;
  const float* pri = (const float*)d_in[0];
  const float* aux = (const float*)d_in[1];
  const float* W1  = (const float*)d_in[2];
  const float* b1  = (const float*)d_in[3];
  const float* W2  = (const float*)d_in[4];
  const float* b2  = (const float*)d_in[5];
  float* out = (float*)d_out;

  const int N = NROWS, D = DDIM;
  char* ws = (char*)d_ws;
  size_t off = 0;
  auto alloc = [&](size_t bytes) -> void* {
    void* p = ws + off;
    off += (bytes + 255) & ~(size_t)255;
    return p;
  };
  // NOTE: prib/auxb, h1b/h2b, p1/p2, n1b/n2b are allocation-adjacent and all
  // sizes are multiples of 256B -> each pair is one contiguous 2N-row matrix.
  u16* prib = (u16*)alloc((size_t)N * D * 2);
  u16* auxb = (u16*)alloc((size_t)N * D * 2);
  u16* W1b  = (u16*)alloc((size_t)D * D * 2);
  u16* W2b  = (u16*)alloc((size_t)D * D * 2);
  u16* h1b  = (u16*)alloc((size_t)N * D * 2);
  u16* h2b  = (u16*)alloc((size_t)N * D * 2);
  float* p1 = (float*)alloc((size_t)N * D * 4);
  float* p2 = (float*)alloc((size_t)N * D * 4);
  u16* n1b  = (u16*)alloc((size_t)N * D * 2);
  u16* n2b  = (u16*)alloc((size_t)N * D * 2);
  float* d12  = (float*)alloc((size_t)N * 4);
  float* rs11 = (float*)alloc((size_t)N * 4);
  float* rs12 = (float*)alloc((size_t)N * 4);
  float* cs12 = (float*)alloc((size_t)N * 4);
  float* rs22 = (float*)alloc((size_t)N * 4);
  (void)auxb; (void)h2b; (void)p2;

  // zero the 4 reduction arrays (contiguous, 32KB each)
  hipMemsetAsync(rs11, 0, (size_t)4 * N * 4, stream);

  // casts
  cast_f32_bf16<<<(N * D / 4 + 255) / 256, 256, 0, stream>>>(pri, prib, N * D / 4);
  cast_f32_bf16<<<(N * D / 4 + 255) / 256, 256, 0, stream>>>(aux, auxb, N * D / 4);
  cast_f32_bf16<<<(D * D / 4 + 255) / 256, 256, 0, stream>>>(W1, W1b, D * D / 4);
  cast_f32_bf16<<<(D * D / 4 + 255) / 256, 256, 0, stream>>>(W2, W2b, D * D / 4);

  // projections over concatenated [pri;aux] rows (M = 2N = 16384):
  // h = elu(z @ W1^T + b1) ; p = h @ W2^T + b2
  dim3 gproj(D / 128, 2 * N / 128);
  gemm_bt<0><<<gproj, 256, 0, stream>>>(prib, W1b, b1, h1b, nullptr, nullptr, nullptr);
  gemm_bt<1><<<gproj, 256, 0, stream>>>(h1b, W2b, b2, nullptr, p1, nullptr, nullptr);

  // normalize + diag(S12)
  normalize_rows<<<N, 256, 0, stream>>>(p1, p2, n1b, n2b, d12);

  // similarity exp-sums: S11/S22 symmetric (upper-triangle grid), S12 full
  dim3 gsim(N / 128, N / 128);
  gemm_bt<3><<<gsim, 256, 0, stream>>>(n1b, n1b, nullptr, nullptr, nullptr, rs11, nullptr);
  gemm_bt<2><<<gsim, 256, 0, stream>>>(n1b, n2b, nullptr, nullptr, nullptr, rs12, cs12);
  gemm_bt<3><<<gsim, 256, 0, stream>>>(n2b, n2b, nullptr, nullptr, nullptr, rs22, nullptr);

  // final scalar
  loss_reduce<<<1, 256, 0, stream>>>(rs11, rs12, cs12, rs22, d12, out);
}

// Round 6
// 413.674 us; speedup vs baseline: 1.3541x; 1.0710x over previous
//
#include <hip/hip_runtime.h>
#include <stdint.h>

typedef unsigned short u16;
typedef __bf16 bf16x8 __attribute__((ext_vector_type(8)));
typedef float f32x4 __attribute__((ext_vector_type(4)));

#define NROWS 8192
#define DDIM 512

// async global->LDS, 16B per lane. Dest must be wave-uniform base + lane*16.
#define GLOAD_LDS16(g, l)                                            \
  __builtin_amdgcn_global_load_lds(                                  \
      (const __attribute__((address_space(1))) void*)(g),            \
      (__attribute__((address_space(3))) void*)(l), 16, 0, 0)

__device__ __forceinline__ u16 f32_to_bf16(float f) {
  union { float f; unsigned u; } v; v.f = f;
  unsigned r = v.u + 0x7fffu + ((v.u >> 16) & 1u);
  return (u16)(r >> 16);
}

// ---------------------------------------------------------------------------
// Shared GEMM core, BK=64: C[i,j] = sum_k A[i,k]*B[j,k], K=512, 128x128 tile,
// 4 waves (2x2), acc 4x4 frags of 16x16x32 MFMA.
// LDS layout: As = [2 halves][128 rows][32 k-elems] (each half 8KB); staging
// writes are lane-linear (thread t owns bytes [t*16,(t+1)*16) of each quarter),
// with the global source chosen so half 0 holds k0..k0+31, half 1 k0+32..k0+63.
// Per K-step: 8 global_load_lds + 2 barriers (vs 16 steps x 2 barriers at BK=32).
// ---------------------------------------------------------------------------
#define GEMM_CORE(A_, B_)                                                     \
  const int t = threadIdx.x;                                                  \
  const int lane = t & 63;                                                    \
  const int w = t >> 6;                                                       \
  const int wr = w >> 1, wc = w & 1;                                          \
  const int r0 = t >> 2, c0 = (t & 3) * 8;                                    \
  const u16* ApA = A_ + (size_t)(tileM + r0) * 512 + c0;                      \
  const u16* ApB = ApA + (size_t)64 * 512;                                    \
  const u16* BpA = B_ + (size_t)(tileN + r0) * 512 + c0;                      \
  const u16* BpB = BpA + (size_t)64 * 512;                                    \
  f32x4 acc[4][4] = {};                                                       \
  const int lrow = lane & 15;                                                 \
  const int kb = (lane >> 4) * 8;                                             \
  for (int k0 = 0; k0 < 512; k0 += 64) {                                      \
    __syncthreads();                                                          \
    GLOAD_LDS16(ApA + k0,      &As[t * 8]);                                   \
    GLOAD_LDS16(ApB + k0,      &As[(t + 256) * 8]);                           \
    GLOAD_LDS16(ApA + k0 + 32, &As[(t + 512) * 8]);                           \
    GLOAD_LDS16(ApB + k0 + 32, &As[(t + 768) * 8]);                           \
    GLOAD_LDS16(BpA + k0,      &Bs[t * 8]);                                   \
    GLOAD_LDS16(BpB + k0,      &Bs[(t + 256) * 8]);                           \
    GLOAD_LDS16(BpA + k0 + 32, &Bs[(t + 512) * 8]);                           \
    GLOAD_LDS16(BpB + k0 + 32, &Bs[(t + 768) * 8]);                           \
    __syncthreads();                                                          \
    _Pragma("unroll")                                                         \
    for (int s = 0; s < 2; s++) {                                             \
      bf16x8 af[4], bfr[4];                                                   \
      _Pragma("unroll")                                                       \
      for (int m = 0; m < 4; m++)                                             \
        af[m] = *(const bf16x8*)&As[s * 4096 + (wr * 64 + m * 16 + lrow) * 32 + kb]; \
      _Pragma("unroll")                                                       \
      for (int n = 0; n < 4; n++)                                             \
        bfr[n] = *(const bf16x8*)&Bs[s * 4096 + (wc * 64 + n * 16 + lrow) * 32 + kb]; \
      _Pragma("unroll")                                                       \
      for (int m = 0; m < 4; m++)                                             \
        _Pragma("unroll")                                                     \
        for (int n = 0; n < 4; n++)                                           \
          acc[m][n] = __builtin_amdgcn_mfma_f32_16x16x32_bf16(af[m], bfr[n], acc[m][n], 0, 0, 0); \
    }                                                                         \
  }                                                                           \
  const int rowg = (lane >> 4) * 4;                                           \
  const int col = lane & 15;

// ---------------- two-segment cast f32 -> bf16 (x4 vectorized) ----------------
__global__ void cast2_f32_bf16(const float* __restrict__ a, u16* __restrict__ oa, int n4a,
                               const float* __restrict__ b, u16* __restrict__ ob, int n4b) {
  int i = blockIdx.x * blockDim.x + threadIdx.x;
  const float* src; u16* dst;
  if (i < n4a) { src = a; dst = oa; }
  else if (i < n4a + n4b) { i -= n4a; src = b; dst = ob; }
  else return;
  float4 v = reinterpret_cast<const float4*>(src)[i];
  ushort4 o;
  o.x = f32_to_bf16(v.x); o.y = f32_to_bf16(v.y);
  o.z = f32_to_bf16(v.z); o.w = f32_to_bf16(v.w);
  reinterpret_cast<ushort4*>(dst)[i] = o;
}

// ---------------- projection GEMMs ----------------
// EPI 0: outB[i,j] = bf16(elu(C + bias[j]));  EPI 1: outF[i,j] = C + bias[j]
template <int EPI>
__global__ void __launch_bounds__(256)
gemm_proj(const u16* __restrict__ Ag, const u16* __restrict__ Bg,
          const float* __restrict__ bias,
          u16* __restrict__ outB, float* __restrict__ outF)
{
  __shared__ __align__(16) u16 As[2 * 128 * 32];
  __shared__ __align__(16) u16 Bs[2 * 128 * 32];
  const int tileM = blockIdx.y * 128;
  const int tileN = blockIdx.x * 128;

  GEMM_CORE(Ag, Bg)

  // epilogue: C/D layout col = lane&15, row = (lane>>4)*4 + reg  [m89/m91]
#pragma unroll
  for (int m = 0; m < 4; m++) {
    int grow = tileM + wr * 64 + m * 16 + rowg;
#pragma unroll
    for (int n = 0; n < 4; n++) {
      int gcol = tileN + wc * 64 + n * 16 + col;
      float bv = bias[gcol];
#pragma unroll
      for (int r = 0; r < 4; r++) {
        float v = acc[m][n][r] + bv;
        if (EPI == 0) {
          v = v > 0.0f ? v : (__expf(v) - 1.0f);
          outB[(size_t)(grow + r) * 512 + gcol] = f32_to_bf16(v);
        } else {
          outF[(size_t)(grow + r) * 512 + gcol] = v;
        }
      }
    }
  }
}

// ---------------- merged similarity exp-sum GEMM (one dispatch) ----------------
// blocks [0,4096): S12 = n1.n2^T full grid -> rowsum rs12, colsum cs12
// blocks [4096,6176): S11 upper-triangle   -> rowsum rs11 (+mirrored col pass)
// blocks [6176,8256): S22 upper-triangle   -> rowsum rs22 (+mirrored col pass)
__global__ void __launch_bounds__(256)
sim_merged(const u16* __restrict__ n1, const u16* __restrict__ n2,
           float* __restrict__ rs11, float* __restrict__ rs12,
           float* __restrict__ cs12, float* __restrict__ rs22)
{
  __shared__ __align__(16) u16 As[2 * 128 * 32];
  __shared__ __align__(16) u16 Bs[2 * 128 * 32];

  int bid = blockIdx.x;
  const u16 *A, *B; float *rsum, *csum; bool sym; int by, bx;
  if (bid < 4096) {
    by = bid >> 6; bx = bid & 63;
    A = n1; B = n2; rsum = rs12; csum = cs12; sym = false;
  } else {
    int tau = bid - 4096;
    if (tau >= 2080) { tau -= 2080; A = n2; rsum = rs22; }
    else             {              A = n1; rsum = rs11; }
    B = A; csum = rsum; sym = true;
    // decode upper-triangle linear index: off(by) = 64*by - by*(by-1)/2
    by = (int)(64.5f - sqrtf(64.5f * 64.5f - 2.0f * (float)tau));
    if (by < 0) by = 0;
    while (64 * (by + 1) - ((by + 1) * by) / 2 <= tau) by++;
    while (64 * by - (by * (by - 1)) / 2 > tau) by--;
    bx = by + (tau - (64 * by - (by * (by - 1)) / 2));
  }
  const int tileM = by * 128, tileN = bx * 128;

  GEMM_CORE(A, B)

  // exp(2C) + row reduction
#pragma unroll
  for (int m = 0; m < 4; m++) {
#pragma unroll
    for (int r = 0; r < 4; r++) {
      float s = 0.0f;
#pragma unroll
      for (int n = 0; n < 4; n++) {
        float e = __expf(acc[m][n][r] * 2.0f);
        acc[m][n][r] = e;
        s += e;
      }
      s += __shfl_xor(s, 1);
      s += __shfl_xor(s, 2);
      s += __shfl_xor(s, 4);
      s += __shfl_xor(s, 8);
      if (col == 0)
        atomicAdd(&rsum[tileM + wr * 64 + m * 16 + rowg + r], s);
    }
  }
  // column reduction: S12 always -> cs12; symmetric off-diag -> mirrored rowsum
  if (!sym || tileM != tileN) {
    float* cdst = sym ? rsum : csum;
#pragma unroll
    for (int n = 0; n < 4; n++) {
      float s = 0.0f;
#pragma unroll
      for (int m = 0; m < 4; m++)
#pragma unroll
        for (int r = 0; r < 4; r++) s += acc[m][n][r];
      s += __shfl_xor(s, 16);
      s += __shfl_xor(s, 32);
      if ((lane >> 4) == 0)
        atomicAdd(&cdst[tileN + wc * 64 + n * 16 + col], s);
    }
  }
}

// ---------------- row-normalize p1,p2 -> bf16; d12[i] = cos(p1_i, p2_i) ----------------
__global__ void __launch_bounds__(256)
normalize_rows(const float* __restrict__ p1, const float* __restrict__ p2,
               u16* __restrict__ n1, u16* __restrict__ n2, float* __restrict__ d12)
{
  int row = blockIdx.x;
  int t = threadIdx.x;
  const float* r1 = p1 + (size_t)row * 512;
  const float* r2 = p2 + (size_t)row * 512;
  float a0 = r1[t], a1 = r1[t + 256];
  float b0 = r2[t], b1 = r2[t + 256];
  float ss1 = a0 * a0 + a1 * a1;
  float ss2 = b0 * b0 + b1 * b1;
  float dt  = a0 * b0 + a1 * b1;
#pragma unroll
  for (int m = 1; m < 64; m <<= 1) {
    ss1 += __shfl_xor(ss1, m);
    ss2 += __shfl_xor(ss2, m);
    dt  += __shfl_xor(dt, m);
  }
  __shared__ float sh[3][4];
  int w = t >> 6;
  if ((t & 63) == 0) { sh[0][w] = ss1; sh[1][w] = ss2; sh[2][w] = dt; }
  __syncthreads();
  ss1 = sh[0][0] + sh[0][1] + sh[0][2] + sh[0][3];
  ss2 = sh[1][0] + sh[1][1] + sh[1][2] + sh[1][3];
  dt  = sh[2][0] + sh[2][1] + sh[2][2] + sh[2][3];
  float i1 = 1.0f / fmaxf(sqrtf(ss1), 1e-12f);
  float i2 = 1.0f / fmaxf(sqrtf(ss2), 1e-12f);
  n1[(size_t)row * 512 + t]       = f32_to_bf16(a0 * i1);
  n1[(size_t)row * 512 + t + 256] = f32_to_bf16(a1 * i1);
  n2[(size_t)row * 512 + t]       = f32_to_bf16(b0 * i2);
  n2[(size_t)row * 512 + t + 256] = f32_to_bf16(b1 * i2);
  if (t == 0) d12[row] = dt * i1 * i2;
}

// ---------------- final loss ----------------
__global__ void __launch_bounds__(256)
loss_reduce(const float* __restrict__ rs11, const float* __restrict__ rs12,
            const float* __restrict__ cs12, const float* __restrict__ rs22,
            const float* __restrict__ d12, float* __restrict__ out)
{
  int t = threadIdx.x;
  const float e2 = __expf(2.0f);
  float s = 0.0f;
  for (int i = t; i < NROWS; i += 256) {
    float den1 = rs11[i] + rs12[i] - e2;
    float den2 = rs22[i] + cs12[i] - e2;
    s += 0.5f * (logf(den1) + logf(den2)) - 2.0f * d12[i];
  }
#pragma unroll
  for (int m = 1; m < 64; m <<= 1) s += __shfl_xor(s, m);
  __shared__ float sh[4];
  if ((t & 63) == 0) sh[t >> 6] = s;
  __syncthreads();
  if (t == 0) out[0] = (sh[0] + sh[1] + sh[2] + sh[3]) * (1.0f / (float)NROWS);
}

extern "C" void kernel_launch(void* const* d_in, const int* in_sizes, int n_in,
                              void* d_out, int out_size, void* d_ws, size_t ws_size,
                              hipStream_t stream) {
  (void)in_sizes; (void)n_in; (void)out_size; (void)ws_size;
  const float* pri = (const float*)d_in[0];
  const float* aux = (const float*)d_in[1];
  const float* W1  = (const float*)d_in[2];
  const float* b1  = (const float*)d_in[3];
  const float* W2  = (const float*)d_in[4];
  const float* b2  = (const float*)d_in[5];
  float* out = (float*)d_out;

  const int N = NROWS, D = DDIM;
  char* ws = (char*)d_ws;
  size_t off = 0;
  auto alloc = [&](size_t bytes) -> void* {
    void* p = ws + off;
    off += (bytes + 255) & ~(size_t)255;
    return p;
  };
  // NOTE: prib/auxb, h1b/h2b, p1/p2 are allocation-adjacent and sizes are
  // multiples of 256B -> each pair is one contiguous 2N-row matrix.
  u16* prib = (u16*)alloc((size_t)N * D * 2);
  u16* auxb = (u16*)alloc((size_t)N * D * 2);
  u16* W1b  = (u16*)alloc((size_t)D * D * 2);
  u16* W2b  = (u16*)alloc((size_t)D * D * 2);
  u16* h1b  = (u16*)alloc((size_t)N * D * 2);
  u16* h2b  = (u16*)alloc((size_t)N * D * 2);
  float* p1 = (float*)alloc((size_t)N * D * 4);
  float* p2 = (float*)alloc((size_t)N * D * 4);
  u16* n1b  = (u16*)alloc((size_t)N * D * 2);
  u16* n2b  = (u16*)alloc((size_t)N * D * 2);
  float* d12  = (float*)alloc((size_t)N * 4);
  float* rs11 = (float*)alloc((size_t)N * 4);
  float* rs12 = (float*)alloc((size_t)N * 4);
  float* cs12 = (float*)alloc((size_t)N * 4);
  float* rs22 = (float*)alloc((size_t)N * 4);
  (void)auxb; (void)h2b; (void)p2;

  // zero the 4 reduction arrays (contiguous, 4x32KB)
  hipMemsetAsync(rs11, 0, (size_t)4 * N * 4, stream);

  // casts (two 2-segment dispatches)
  const int n4e = N * D / 4, n4w = D * D / 4;
  cast2_f32_bf16<<<(n4e + n4w + 255) / 256, 256, 0, stream>>>(pri, prib, n4e, W1, W1b, n4w);
  cast2_f32_bf16<<<(n4e + n4w + 255) / 256, 256, 0, stream>>>(aux, auxb, n4e, W2, W2b, n4w);

  // projections over concatenated [pri;aux] rows (M = 2N = 16384):
  // h = elu(z @ W1^T + b1) ; p = h @ W2^T + b2
  dim3 gproj(D / 128, 2 * N / 128);
  gemm_proj<0><<<gproj, 256, 0, stream>>>(prib, W1b, b1, h1b, nullptr);
  gemm_proj<1><<<gproj, 256, 0, stream>>>(h1b, W2b, b2, nullptr, p1);

  // normalize + diag(S12)
  normalize_rows<<<N, 256, 0, stream>>>(p1, p2, n1b, n2b, d12);

  // all three similarity exp-sums in one dispatch
  sim_merged<<<4096 + 2 * 2080, 256, 0, stream>>>(n1b, n2b, rs11, rs12, cs12, rs22);

  // final scalar
  loss_reduce<<<1, 256, 0, stream>>>(rs11, rs12, cs12, rs22, d12, out);
}